// Round 8
// baseline (671.505 us; speedup 1.0000x reference)
//
#include <hip/hip_runtime.h>
#include <hip/hip_fp16.h>

// GraphNN_KNN: N=50000 nodes, E=800000 edges, H=64.
// msg = relu([x_i, x_j-x_i, ef] @ W + b) == relu(u[dst] + v[src] + ef*we)
// with u = x@(Wt-Wm)+b, v = x@Wm. All node GEMMs (u/v, lin1/2): MFMA
// 16x16x32_f16 split-fp16 (x=xh+xl, W=Wh+Wl; 3 terms) for ~fp32 accuracy;
// u/v stored fp16 for gathers. R8: fuse node-local chains into single
// kernels with LDS handoff (em(o)+uv(o+1), em3+lin+uv0, em3+uv_ec, ec+uv_ec),
// ping-pong u/v sets to break the gather/write race; uv B-frags read directly
// from global (L2-resident) -> LDS 27.7KB, 5 blocks/CU.

#define NN 50000
#define NE 800000
#define PER 200000      // E / 4 orders
#define HD 64
#define NKEY 250112     // 4*NN em keys + NN ec keys, padded to 977*256

#define NB_COUNT 3125
#define NB_LIN   782
#define NB_PREP  224    // 14 mats * 4096 / 256

typedef _Float16 half8 __attribute__((ext_vector_type(8)));
typedef float float4v __attribute__((ext_vector_type(4)));

// ---------------- fused setup: count + lin0 + prep_w -----------------------
// blocks [0,3125): edge count (atomic rank capture)
// blocks [3125,3907): x = relu(x_in @ lin0_w + lin0_b)   (K=10)
// blocks [3907,4131): split-fp16 weight prep:
//   mats 0-2 emWu, 3-5 emWv, 6-8 ecWu, 9-11 ecWv, 12 lin1, 13 lin2 (hi);
//   lo parts at mat+14. All transposed to [n][k].
__global__ __launch_bounds__(256) void setup_kernel(
        const int* __restrict__ ei, int* __restrict__ cnt,
        uchar2* __restrict__ rank,
        const float* __restrict__ x_in, const float* __restrict__ lw0,
        const float* __restrict__ lb0, float* __restrict__ x,
        const float* __restrict__ em_w, const float* __restrict__ ec_w,
        const float* __restrict__ lw1, const float* __restrict__ lw2,
        _Float16* __restrict__ wh) {
    __shared__ float xs[64][11];
    int t = threadIdx.x;
    int b = blockIdx.x;
    if (b < NB_COUNT) {
        int e = b * 256 + t;
        if (e >= NE) return;
        int src = ei[e];
        int dst = ei[NE + e];
        int o = e / PER;
        int r1 = atomicAdd(&cnt[o * NN + src], 1);
        int r2 = atomicAdd(&cnt[4 * NN + dst], 1);
        rank[e] = make_uchar2((unsigned char)r1, (unsigned char)r2);
    } else if (b < NB_COUNT + NB_LIN) {
        int n0 = (b - NB_COUNT) * 64;
        for (int idx = t; idx < 64 * 10; idx += 256) {
            int n = idx / 10, k = idx - n * 10;
            int g = n0 + n;
            xs[n][k] = (g < NN) ? x_in[(size_t)g * 10 + k] : 0.f;
        }
        __syncthreads();
        int ng = t >> 4;
        int f0 = (t & 15) * 4;
        float acc[4][4] = {};
        for (int k = 0; k < 10; ++k) {
            float4 w4 = *(const float4*)&lw0[k * HD + f0];
            #pragma unroll
            for (int j = 0; j < 4; ++j) {
                float xv = xs[ng * 4 + j][k];
                acc[j][0] += xv * w4.x; acc[j][1] += xv * w4.y;
                acc[j][2] += xv * w4.z; acc[j][3] += xv * w4.w;
            }
        }
        float4 b4 = *(const float4*)&lb0[f0];
        #pragma unroll
        for (int j = 0; j < 4; ++j) {
            int g = n0 + ng * 4 + j;
            if (g < NN) {
                float4 o;
                o.x = fmaxf(acc[j][0] + b4.x, 0.f);
                o.y = fmaxf(acc[j][1] + b4.y, 0.f);
                o.z = fmaxf(acc[j][2] + b4.z, 0.f);
                o.w = fmaxf(acc[j][3] + b4.w, 0.f);
                *(float4*)&x[(size_t)g * HD + f0] = o;
            }
        }
    } else {
        int idx = (b - NB_COUNT - NB_LIN) * 256 + t;   // < 14*4096
        int mat = idx >> 12, pos = idx & 4095;
        int n = pos >> 6, k = pos & 63;
        float val;
        if (mat < 3)       { const float* B = em_w + mat * 129 * 64;     val = B[k*64+n] - B[(64+k)*64+n]; }
        else if (mat < 6)  { const float* B = em_w + (mat-3) * 129 * 64; val = B[(64+k)*64+n]; }
        else if (mat < 9)  { const float* B = ec_w + (mat-6) * 128 * 64; val = B[k*64+n] - B[(64+k)*64+n]; }
        else if (mat < 12) { const float* B = ec_w + (mat-9) * 128 * 64; val = B[(64+k)*64+n]; }
        else               { const float* B = (mat == 12) ? lw1 : lw2;   val = B[k*64+n]; }
        _Float16 h = (_Float16)val;
        _Float16 l = (_Float16)(val - (float)h);
        wh[(size_t)mat * 4096 + n * 64 + k] = h;
        wh[(size_t)(14 + mat) * 4096 + n * 64 + k] = l;
    }
}

// ---------------- scans ----------------
__global__ __launch_bounds__(256) void scan_blk(
        const int* __restrict__ cnt, int* __restrict__ bsum) {
    __shared__ int s[256];
    int t = threadIdx.x;
    int i = blockIdx.x * 256 + t;
    int c = (i < NKEY) ? cnt[i] : 0;
    s[t] = c; __syncthreads();
    for (int d = 1; d < 256; d <<= 1) {
        int v = (t >= d) ? s[t - d] : 0;
        __syncthreads(); s[t] += v; __syncthreads();
    }
    if (t == 255) bsum[blockIdx.x] = s[255];
}

__global__ __launch_bounds__(1024) void scan_top(
        const int* __restrict__ bsum, int* __restrict__ bofs, int nb) {
    __shared__ int s[1024];
    int t = threadIdx.x;
    int c = (t < nb) ? bsum[t] : 0;
    s[t] = c; __syncthreads();
    for (int d = 1; d < 1024; d <<= 1) {
        int v = (t >= d) ? s[t - d] : 0;
        __syncthreads(); s[t] += v; __syncthreads();
    }
    if (t < nb) bofs[t] = s[t] - c;  // exclusive
}

__global__ __launch_bounds__(256) void scan_fin(
        const int* __restrict__ cnt, const int* __restrict__ bofs,
        int* __restrict__ ofs) {
    __shared__ int s[256];
    int t = threadIdx.x;
    int i = blockIdx.x * 256 + t;
    int c = (i < NKEY) ? cnt[i] : 0;
    s[t] = c; __syncthreads();
    for (int d = 1; d < 256; d <<= 1) {
        int v = (t >= d) ? s[t - d] : 0;
        __syncthreads(); s[t] += v; __syncthreads();
    }
    if (i < NKEY) ofs[i] = bofs[blockIdx.x] + s[t] - c;  // exclusive
}

// fill (no atomics): em value = dst<<16 | fp16(ef) bits; ec value = src
__global__ __launch_bounds__(256) void fill_kernel(
        const int* __restrict__ ei, const float* __restrict__ ef,
        const int* __restrict__ ofs, const uchar2* __restrict__ rank,
        unsigned* __restrict__ em_val, int* __restrict__ ec_val) {
    int e = blockIdx.x * 256 + threadIdx.x;
    if (e >= NE) return;
    int src = ei[e];
    int dst = ei[NE + e];
    int o = e / PER;
    uchar2 r = rank[e];
    int p1 = ofs[o * NN + src] + r.x;
    unsigned short eb = __half_as_ushort(__float2half_rn(ef[e]));
    em_val[p1] = ((unsigned)dst << 16) | (unsigned)eb;
    int p2 = ofs[4 * NN + dst] + r.y - NE;
    ec_val[p2] = src;
}

// load 8 consecutive halves (16B aligned) -> 8 floats
__device__ __forceinline__ void load_h8(const __half* p, float* o) {
    float4 r = *(const float4*)p;
    __half2 h0 = *reinterpret_cast<__half2*>(&r.x);
    __half2 h1 = *reinterpret_cast<__half2*>(&r.y);
    __half2 h2 = *reinterpret_cast<__half2*>(&r.z);
    __half2 h3 = *reinterpret_cast<__half2*>(&r.w);
    float2 f0 = __half22float2(h0), f1 = __half22float2(h1);
    float2 f2 = __half22float2(h2), f3 = __half22float2(h3);
    o[0] = f0.x; o[1] = f0.y; o[2] = f1.x; o[3] = f1.y;
    o[4] = f2.x; o[5] = f2.y; o[6] = f3.x; o[7] = f3.y;
}

__device__ __forceinline__ void split8(const float* f, half8& h, half8& l) {
    #pragma unroll
    for (int j = 0; j < 8; ++j) {
        _Float16 hh = (_Float16)f[j];
        h[j] = hh; l[j] = (_Float16)(f[j] - (float)hh);
    }
}

#define MFMA16(A, B, C) __builtin_amdgcn_mfma_f32_16x16x32_f16(A, B, C, 0, 0, 0)

// ---------------- fused pre-aggregate + (lin) + uv GEMM --------------------
// 64 nodes/block, 4 waves. PRE: 0 = stage x from global; 1 = em pass (fold
// into x, optional global write); 2 = ec pass (max-agg, no x io). DOLIN:
// x'' = relu(x'@Wl + lb) via MFMA before the uv GEMM (also writes x'' global).
// uv: u = x@Wu + b, v = x@Wv; B-frags straight from global (L2-resident).
// em/ec gather from (ug,vg) = previous uv's output set; (u,v) = next set.
template<int PRE, bool WRITEX, bool DOLIN>
__global__ __launch_bounds__(256) void fused_uv(
        const float* __restrict__ xg, float* __restrict__ xout,
        const unsigned* __restrict__ em_val, const int* __restrict__ ec_val,
        const int* __restrict__ ofs, int order,
        const __half* __restrict__ ug, const __half* __restrict__ vg,
        const float* __restrict__ we,
        const _Float16* __restrict__ Wlh, const _Float16* __restrict__ Wll,
        const float* __restrict__ lbias,
        const _Float16* __restrict__ Wuh, const _Float16* __restrict__ Wul,
        const _Float16* __restrict__ Wvh, const _Float16* __restrict__ Wvl,
        const float* __restrict__ bias,
        _Float16* __restrict__ u, _Float16* __restrict__ v) {
    __shared__ _Float16 xh[64 * 72], xl[64 * 72];
    __shared__ _Float16 rp[4 * 16 * 72];
    const int t = threadIdx.x;
    const int n0 = blockIdx.x * 64;

    if constexpr (PRE == 0) {
        int node = t >> 2, k0 = (t & 3) * 16;
        int g = n0 + node;
        float f[16];
        if (g < NN) {
            const float4* xr4 = (const float4*)&xg[(size_t)g * HD + k0];
            *(float4*)&f[0] = xr4[0]; *(float4*)&f[4] = xr4[1];
            *(float4*)&f[8] = xr4[2]; *(float4*)&f[12] = xr4[3];
        } else {
            #pragma unroll
            for (int j = 0; j < 16; ++j) f[j] = 0.f;
        }
        half8 h0, l0, h1, l1;
        split8(f, h0, l0); split8(f + 8, h1, l1);
        *(half8*)&xh[node * 72 + k0] = h0; *(half8*)&xh[node * 72 + k0 + 8] = h1;
        *(half8*)&xl[node * 72 + k0] = l0; *(half8*)&xl[node * 72 + k0 + 8] = l1;
    } else if constexpr (PRE == 1) {
        int f0 = (t & 7) * 8;
        float wef[8];
        *(float4*)&wef[0] = *(const float4*)&we[f0];
        *(float4*)&wef[4] = *(const float4*)&we[f0 + 4];
        #pragma unroll
        for (int hv = 0; hv < 2; ++hv) {
            int nl = (t >> 3) + hv * 32;
            int node = n0 + nl;
            float xr[8];
            if (node < NN) {
                int key = order * NN + node;
                int s0 = ofs[key], s1 = ofs[key + 1];
                float vn[8], acc[8] = {};
                load_h8(&vg[(size_t)node * HD + f0], vn);
                int p = s0;
                for (; p + 2 <= s1; p += 2) {
                    unsigned e0 = em_val[p], e1 = em_val[p + 1];
                    float u0[8], u1[8];
                    load_h8(&ug[(size_t)(e0 >> 16) * HD + f0], u0);
                    load_h8(&ug[(size_t)(e1 >> 16) * HD + f0], u1);
                    float ef0 = __half2float(__ushort_as_half((unsigned short)(e0 & 0xffff)));
                    float ef1 = __half2float(__ushort_as_half((unsigned short)(e1 & 0xffff)));
                    #pragma unroll
                    for (int j = 0; j < 8; ++j) {
                        acc[j] += fmaxf(u0[j] + vn[j] + ef0 * wef[j], 0.f)
                                + fmaxf(u1[j] + vn[j] + ef1 * wef[j], 0.f);
                    }
                }
                if (p < s1) {
                    unsigned e0 = em_val[p];
                    float u0[8];
                    load_h8(&ug[(size_t)(e0 >> 16) * HD + f0], u0);
                    float ef0 = __half2float(__ushort_as_half((unsigned short)(e0 & 0xffff)));
                    #pragma unroll
                    for (int j = 0; j < 8; ++j)
                        acc[j] += fmaxf(u0[j] + vn[j] + ef0 * wef[j], 0.f);
                }
                *(float4*)&xr[0] = *(const float4*)&xg[(size_t)node * HD + f0];
                *(float4*)&xr[4] = *(const float4*)&xg[(size_t)node * HD + f0 + 4];
                #pragma unroll
                for (int j = 0; j < 8; ++j) xr[j] = (xr[j] + acc[j]) * 0.5f;
                if constexpr (WRITEX) {
                    *(float4*)&xout[(size_t)node * HD + f0] = *(float4*)&xr[0];
                    *(float4*)&xout[(size_t)node * HD + f0 + 4] = *(float4*)&xr[4];
                }
            } else {
                #pragma unroll
                for (int j = 0; j < 8; ++j) xr[j] = 0.f;
            }
            half8 hh, ll;
            split8(xr, hh, ll);
            *(half8*)&xh[nl * 72 + f0] = hh;
            *(half8*)&xl[nl * 72 + f0] = ll;
        }
    } else {  // PRE == 2: edge conv max-agg
        int f0 = (t & 7) * 8;
        #pragma unroll
        for (int hv = 0; hv < 2; ++hv) {
            int nl = (t >> 3) + hv * 32;
            int node = n0 + nl;
            float m[8] = {};
            if (node < NN) {
                int s0 = ofs[4 * NN + node] - NE, s1 = ofs[4 * NN + node + 1] - NE;
                float un[8];
                load_h8(&ug[(size_t)node * HD + f0], un);
                int p = s0;
                for (; p + 2 <= s1; p += 2) {
                    int i0 = ec_val[p], i1 = ec_val[p + 1];
                    float v0[8], v1[8];
                    load_h8(&vg[(size_t)i0 * HD + f0], v0);
                    load_h8(&vg[(size_t)i1 * HD + f0], v1);
                    #pragma unroll
                    for (int j = 0; j < 8; ++j)
                        m[j] = fmaxf(m[j], fmaxf(un[j] + v0[j], un[j] + v1[j]));
                }
                if (p < s1) {
                    int i0 = ec_val[p];
                    float v0[8];
                    load_h8(&vg[(size_t)i0 * HD + f0], v0);
                    #pragma unroll
                    for (int j = 0; j < 8; ++j) m[j] = fmaxf(m[j], un[j] + v0[j]);
                }
            }
            half8 hh, ll;
            split8(m, hh, ll);
            *(half8*)&xh[nl * 72 + f0] = hh;
            *(half8*)&xl[nl * 72 + f0] = ll;
        }
    }
    __syncthreads();

    const int w = t >> 6, lane = t & 63;
    const int quad = lane >> 4, l16 = lane & 15;
    const int m0 = w * 16;

    half8 ah0 = *(half8*)&xh[(m0 + l16) * 72 + quad * 8];
    half8 ah1 = *(half8*)&xh[(m0 + l16) * 72 + 32 + quad * 8];
    half8 al0 = *(half8*)&xl[(m0 + l16) * 72 + quad * 8];
    half8 al1 = *(half8*)&xl[(m0 + l16) * 72 + 32 + quad * 8];

    if constexpr (DOLIN) {
        // x'' = relu(x' @ Wl + lb), then restage for the uv GEMM
        float4v ax[4];
        #pragma unroll
        for (int nt = 0; nt < 4; ++nt) {
            int n = nt * 16 + l16;
            half8 bh0 = *(const half8*)&Wlh[n * 64 + quad * 8];
            half8 bh1 = *(const half8*)&Wlh[n * 64 + 32 + quad * 8];
            half8 bl0 = *(const half8*)&Wll[n * 64 + quad * 8];
            half8 bl1 = *(const half8*)&Wll[n * 64 + 32 + quad * 8];
            float4v acc = {0.f, 0.f, 0.f, 0.f};
            acc = MFMA16(ah0, bh0, acc); acc = MFMA16(ah1, bh1, acc);
            acc = MFMA16(al0, bh0, acc); acc = MFMA16(al1, bh1, acc);
            acc = MFMA16(ah0, bl0, acc); acc = MFMA16(ah1, bl1, acc);
            ax[nt] = acc;
        }
        __syncthreads();   // all A-frag reads of xh/xl complete
        #pragma unroll
        for (int nt = 0; nt < 4; ++nt) {
            float bn = lbias[nt * 16 + l16];
            #pragma unroll
            for (int r = 0; r < 4; ++r) {
                float val = fmaxf(ax[nt][r] + bn, 0.f);
                int mrow = m0 + quad * 4 + r;
                _Float16 hh = (_Float16)val;
                xh[mrow * 72 + nt * 16 + l16] = hh;
                xl[mrow * 72 + nt * 16 + l16] = (_Float16)(val - (float)hh);
                int gn = n0 + mrow;
                if (gn < NN) xout[(size_t)gn * HD + nt * 16 + l16] = val;
            }
        }
        __syncthreads();
        ah0 = *(half8*)&xh[(m0 + l16) * 72 + quad * 8];
        ah1 = *(half8*)&xh[(m0 + l16) * 72 + 32 + quad * 8];
        al0 = *(half8*)&xl[(m0 + l16) * 72 + quad * 8];
        al1 = *(half8*)&xl[(m0 + l16) * 72 + 32 + quad * 8];
    }

    float4v au[4], av[4];
    #pragma unroll
    for (int nt = 0; nt < 4; ++nt) {
        int n = nt * 16 + l16;
        half8 bh0 = *(const half8*)&Wuh[n * 64 + quad * 8];
        half8 bh1 = *(const half8*)&Wuh[n * 64 + 32 + quad * 8];
        half8 bl0 = *(const half8*)&Wul[n * 64 + quad * 8];
        half8 bl1 = *(const half8*)&Wul[n * 64 + 32 + quad * 8];
        float4v acc = {0.f, 0.f, 0.f, 0.f};
        acc = MFMA16(ah0, bh0, acc); acc = MFMA16(ah1, bh1, acc);
        acc = MFMA16(al0, bh0, acc); acc = MFMA16(al1, bh1, acc);
        acc = MFMA16(ah0, bl0, acc); acc = MFMA16(ah1, bl1, acc);
        au[nt] = acc;
        half8 ch0 = *(const half8*)&Wvh[n * 64 + quad * 8];
        half8 ch1 = *(const half8*)&Wvh[n * 64 + 32 + quad * 8];
        half8 cl0 = *(const half8*)&Wvl[n * 64 + quad * 8];
        half8 cl1 = *(const half8*)&Wvl[n * 64 + 32 + quad * 8];
        float4v accv = {0.f, 0.f, 0.f, 0.f};
        accv = MFMA16(ah0, ch0, accv); accv = MFMA16(ah1, ch1, accv);
        accv = MFMA16(al0, ch0, accv); accv = MFMA16(al1, ch1, accv);
        accv = MFMA16(ah0, cl0, accv); accv = MFMA16(ah1, cl1, accv);
        av[nt] = accv;
    }

    // repack u (+bias) through per-wave LDS, store 16B vectors
    _Float16* rpw = &rp[w * 16 * 72];
    #pragma unroll
    for (int nt = 0; nt < 4; ++nt) {
        float bn = bias[nt * 16 + l16];
        #pragma unroll
        for (int r = 0; r < 4; ++r)
            rpw[(quad * 4 + r) * 72 + nt * 16 + l16] = (_Float16)(au[nt][r] + bn);
    }
    int mr = lane >> 2, cr = (lane & 3) * 16;
    int gr = n0 + m0 + mr;
    if (gr < NN) {
        *(half8*)&u[(size_t)gr * HD + cr]     = *(half8*)&rpw[mr * 72 + cr];
        *(half8*)&u[(size_t)gr * HD + cr + 8] = *(half8*)&rpw[mr * 72 + cr + 8];
    }
    #pragma unroll
    for (int nt = 0; nt < 4; ++nt) {
        #pragma unroll
        for (int r = 0; r < 4; ++r)
            rpw[(quad * 4 + r) * 72 + nt * 16 + l16] = (_Float16)(av[nt][r]);
    }
    if (gr < NN) {
        *(half8*)&v[(size_t)gr * HD + cr]     = *(half8*)&rpw[mr * 72 + cr];
        *(half8*)&v[(size_t)gr * HD + cr + 8] = *(half8*)&rpw[mr * 72 + cr + 8];
    }
}

// ---------------- last ec pass fused with output projection ----------------
__global__ __launch_bounds__(256) void ec_out(
        const int* __restrict__ ec_val, const int* __restrict__ ofs,
        const __half* __restrict__ u, const __half* __restrict__ v,
        const float* __restrict__ ow, const float* __restrict__ ob,
        float* __restrict__ out) {
    __shared__ float xs[32][72];
    int t = threadIdx.x;
    int nl = t >> 3;                     // local node 0..31
    int node = blockIdx.x * 32 + nl;
    int f0 = (t & 7) * 8;
    float m[8] = {};
    if (node < NN) {
        int s0 = ofs[4 * NN + node] - NE, s1 = ofs[4 * NN + node + 1] - NE;
        float un[8];
        load_h8(&u[(size_t)node * HD + f0], un);
        int p = s0;
        for (; p + 2 <= s1; p += 2) {
            int i0 = ec_val[p], i1 = ec_val[p + 1];
            float v0[8], v1[8];
            load_h8(&v[(size_t)i0 * HD + f0], v0);
            load_h8(&v[(size_t)i1 * HD + f0], v1);
            #pragma unroll
            for (int j = 0; j < 8; ++j)
                m[j] = fmaxf(m[j], fmaxf(un[j] + v0[j], un[j] + v1[j]));
        }
        if (p < s1) {
            int i0 = ec_val[p];
            float v0[8];
            load_h8(&v[(size_t)i0 * HD + f0], v0);
            #pragma unroll
            for (int j = 0; j < 8; ++j) m[j] = fmaxf(m[j], un[j] + v0[j]);
        }
    }
    #pragma unroll
    for (int j = 0; j < 8; ++j) xs[nl][f0 + j] = m[j];
    __syncthreads();
    for (int idx = t; idx < 32 * 10; idx += 256) {
        int n = idx / 10, f = idx - n * 10;
        int g = blockIdx.x * 32 + n;
        if (g >= NN) continue;
        float acc = ob[f];
        #pragma unroll
        for (int k = 0; k < HD; ++k) acc += xs[n][k] * ow[k * 10 + f];
        out[(size_t)g * 10 + f] = acc;
    }
}

extern "C" void kernel_launch(void* const* d_in, const int* in_sizes, int n_in,
                              void* d_out, int out_size, void* d_ws, size_t ws_size,
                              hipStream_t stream) {
    const float* x_in  = (const float*)d_in[0];
    const int*   ei    = (const int*)d_in[1];
    const float* ef    = (const float*)d_in[2];
    const float* lw[3] = {(const float*)d_in[3], (const float*)d_in[5], (const float*)d_in[7]};
    const float* lb[3] = {(const float*)d_in[4], (const float*)d_in[6], (const float*)d_in[8]};
    const float* em_w  = (const float*)d_in[9];
    const float* em_b  = (const float*)d_in[10];
    const float* ec_w  = (const float*)d_in[11];
    const float* ec_b  = (const float*)d_in[12];
    const float* ow    = (const float*)d_in[13];
    const float* ob    = (const float*)d_in[14];
    float* out = (float*)d_out;

    char* wsb = (char*)d_ws;
    size_t off = 0;
    auto alloc = [&](size_t bytes) {
        void* p = wsb + off;
        off = (off + bytes + 255) & ~(size_t)255;
        return p;
    };
    float*     x      = (float*)alloc((size_t)NN * HD * 4);
    _Float16*  uA     = (_Float16*)alloc((size_t)NN * HD * 2);
    _Float16*  vA     = (_Float16*)alloc((size_t)NN * HD * 2);
    _Float16*  uB     = (_Float16*)alloc((size_t)NN * HD * 2);
    _Float16*  vB     = (_Float16*)alloc((size_t)NN * HD * 2);
    int*       cnt    = (int*)alloc((size_t)NKEY * 4);
    int*       ofs    = (int*)alloc((size_t)NKEY * 4);
    int*       bsum   = (int*)alloc((size_t)1024 * 4);
    int*       bofs   = (int*)alloc((size_t)1024 * 4);
    uchar2*    rank   = (uchar2*)alloc((size_t)NE * 2);
    unsigned*  em_val = (unsigned*)alloc((size_t)NE * 4);
    int*       ec_val = (int*)alloc((size_t)NE * 4);
    _Float16*  wh     = (_Float16*)alloc((size_t)28 * 4096 * 2);
    (void)ws_size; (void)in_sizes; (void)n_in; (void)out_size;

    const int gb_nodes = (NN + 63) / 64;   // 782
    const int gb_edges = (NE + 255) / 256; // 3125
    const int gb_n8    = (NN + 31) / 32;   // 1563
    const int gb_keys  = NKEY / 256;       // 977

    // weight pointer helpers (hi mats 0..13, lo at +14)
    auto Wm = [&](int mat) { return wh + (size_t)mat * 4096; };
    auto Wl_ = [&](int mat) { return wh + (size_t)(14 + mat) * 4096; };

    // ---- setup: count + lin0 + prep_w fused; then scan + fill ----
    hipMemsetAsync(cnt, 0, (size_t)NKEY * 4, stream);
    setup_kernel<<<NB_COUNT + NB_LIN + NB_PREP, 256, 0, stream>>>(
        ei, cnt, rank, x_in, lw[0], lb[0], x, em_w, ec_w, lw[1], lw[2], wh);
    scan_blk<<<gb_keys, 256, 0, stream>>>(cnt, bsum);
    scan_top<<<1, 1024, 0, stream>>>(bsum, bofs, gb_keys);
    scan_fin<<<gb_keys, 256, 0, stream>>>(cnt, bofs, ofs);
    fill_kernel<<<gb_edges, 256, 0, stream>>>(ei, ef, ofs, rank, em_val, ec_val);

    // ---- network ----
    _Float16 *cu = uA, *cv = vA, *nu = uB, *nv = vB;
    auto swapbuf = [&]() { _Float16* t1 = cu; cu = nu; nu = t1;
                           _Float16* t2 = cv; cv = nv; nv = t2; };

    // uv0: stage x (lin0 output) -> u/v with layer-0 em weights -> cu
    fused_uv<0, false, false><<<gb_nodes, 256, 0, stream>>>(
        x, nullptr, nullptr, nullptr, nullptr, 0, nullptr, nullptr, nullptr,
        nullptr, nullptr, nullptr,
        Wm(0), Wl_(0), Wm(3), Wl_(3), em_b, cu, cv);

    for (int i = 0; i < 3; ++i) {
        const float* we = em_w + (size_t)i * 129 * HD + 128 * HD;
        const float* bi = em_b + (size_t)i * HD;
        // em(o) + uv(o+1) with this layer's weights
        for (int o = 0; o < 3; ++o) {
            fused_uv<1, true, false><<<gb_nodes, 256, 0, stream>>>(
                x, x, em_val, nullptr, ofs, o, (const __half*)cu, (const __half*)cv,
                we, nullptr, nullptr, nullptr,
                Wm(i), Wl_(i), Wm(3 + i), Wl_(3 + i), bi, nu, nv);
            swapbuf();
        }
        if (i < 2) {
            // em3 + lin(i+1) + uv with layer i+1's em weights
            fused_uv<1, false, true><<<gb_nodes, 256, 0, stream>>>(
                x, x, em_val, nullptr, ofs, 3, (const __half*)cu, (const __half*)cv,
                we, Wm(12 + i), Wl_(12 + i), lb[i + 1],
                Wm(i + 1), Wl_(i + 1), Wm(4 + i), Wl_(4 + i),
                em_b + (size_t)(i + 1) * HD, nu, nv);
            swapbuf();
        } else {
            // em3(L2) + uv with ec0 weights (no x write needed)
            fused_uv<1, false, false><<<gb_nodes, 256, 0, stream>>>(
                x, nullptr, em_val, nullptr, ofs, 3, (const __half*)cu, (const __half*)cv,
                we, nullptr, nullptr, nullptr,
                Wm(6), Wl_(6), Wm(9), Wl_(9), ec_b, nu, nv);
            swapbuf();
        }
    }

    // ec(j) + uv with ec(j+1) weights, j = 0,1
    for (int j = 0; j < 2; ++j) {
        fused_uv<2, false, false><<<gb_nodes, 256, 0, stream>>>(
            nullptr, nullptr, nullptr, ec_val, ofs, 0,
            (const __half*)cu, (const __half*)cv, nullptr,
            nullptr, nullptr, nullptr,
            Wm(7 + j), Wl_(7 + j), Wm(10 + j), Wl_(10 + j),
            ec_b + (size_t)(j + 1) * HD, nu, nv);
        swapbuf();
    }

    // ec2 + output projection
    ec_out<<<gb_n8, 256, 0, stream>>>(ec_val, ofs, (const __half*)cu,
                                      (const __half*)cv, ow, ob, out);
}

// Round 9
// 591.831 us; speedup vs baseline: 1.1346x; 1.1346x over previous
//
#include <hip/hip_runtime.h>
#include <hip/hip_fp16.h>

// GraphNN_KNN: N=50000 nodes, E=800000 edges, H=64.
// msg = relu([x_i, x_j-x_i, ef] @ W + b) == relu(u[dst] + v[src] + ef*we)
// with u = x@(Wt-Wm)+b, v = x@Wm. Node GEMMs: MFMA 16x16x32_f16 split-fp16
// (x=xh+xl, W=Wh+Wl; 3 terms) for ~fp32 accuracy; u/v stored fp16.
// Edge passes: standalone kernels, 8 nodes/wave, 8 lanes/node, 16B gathers
// (R8 post-mortem: fusing gather into the GEMM block halves gather
// parallelism and adds barrier tail latency -> keep split).
// R9: fill || uv0 co-launch (independent); lin+uv fused (node-local, no
// gather); ec 4-edge unroll; everything else = known-good R5/R7 kernels.

#define NN 50000
#define NE 800000
#define PER 200000      // E / 4 orders
#define HD 64
#define NKEY 250112     // 4*NN em keys + NN ec keys, padded to 977*256

#define NB_COUNT 3125
#define NB_LIN   782
#define NB_PREP  224    // 14 mats * 4096 / 256

typedef _Float16 half8 __attribute__((ext_vector_type(8)));
typedef float float4v __attribute__((ext_vector_type(4)));

#define MFMA16(A, B, C) __builtin_amdgcn_mfma_f32_16x16x32_f16(A, B, C, 0, 0, 0)

// ---------------- fused setup: count + lin0 + prep_w -----------------------
// blocks [0,3125): edge count (atomic rank capture)
// blocks [3125,3907): x = relu(x_in @ lin0_w + lin0_b)   (K=10)
// blocks [3907,4131): split-fp16 weight prep:
//   mats 0-2 emWu, 3-5 emWv, 6-8 ecWu, 9-11 ecWv, 12 lin1, 13 lin2 (hi);
//   lo parts at mat+14. All transposed to [n][k].
__global__ __launch_bounds__(256) void setup_kernel(
        const int* __restrict__ ei, int* __restrict__ cnt,
        uchar2* __restrict__ rank,
        const float* __restrict__ x_in, const float* __restrict__ lw0,
        const float* __restrict__ lb0, float* __restrict__ x,
        const float* __restrict__ em_w, const float* __restrict__ ec_w,
        const float* __restrict__ lw1, const float* __restrict__ lw2,
        _Float16* __restrict__ wh) {
    __shared__ float xs[64][11];
    int t = threadIdx.x;
    int b = blockIdx.x;
    if (b < NB_COUNT) {
        int e = b * 256 + t;
        if (e >= NE) return;
        int src = ei[e];
        int dst = ei[NE + e];
        int o = e / PER;
        int r1 = atomicAdd(&cnt[o * NN + src], 1);
        int r2 = atomicAdd(&cnt[4 * NN + dst], 1);
        rank[e] = make_uchar2((unsigned char)r1, (unsigned char)r2);
    } else if (b < NB_COUNT + NB_LIN) {
        int n0 = (b - NB_COUNT) * 64;
        for (int idx = t; idx < 64 * 10; idx += 256) {
            int n = idx / 10, k = idx - n * 10;
            int g = n0 + n;
            xs[n][k] = (g < NN) ? x_in[(size_t)g * 10 + k] : 0.f;
        }
        __syncthreads();
        int ng = t >> 4;
        int f0 = (t & 15) * 4;
        float acc[4][4] = {};
        for (int k = 0; k < 10; ++k) {
            float4 w4 = *(const float4*)&lw0[k * HD + f0];
            #pragma unroll
            for (int j = 0; j < 4; ++j) {
                float xv = xs[ng * 4 + j][k];
                acc[j][0] += xv * w4.x; acc[j][1] += xv * w4.y;
                acc[j][2] += xv * w4.z; acc[j][3] += xv * w4.w;
            }
        }
        float4 b4 = *(const float4*)&lb0[f0];
        #pragma unroll
        for (int j = 0; j < 4; ++j) {
            int g = n0 + ng * 4 + j;
            if (g < NN) {
                float4 o;
                o.x = fmaxf(acc[j][0] + b4.x, 0.f);
                o.y = fmaxf(acc[j][1] + b4.y, 0.f);
                o.z = fmaxf(acc[j][2] + b4.z, 0.f);
                o.w = fmaxf(acc[j][3] + b4.w, 0.f);
                *(float4*)&x[(size_t)g * HD + f0] = o;
            }
        }
    } else {
        int idx = (b - NB_COUNT - NB_LIN) * 256 + t;   // < 14*4096
        int mat = idx >> 12, pos = idx & 4095;
        int n = pos >> 6, k = pos & 63;
        float val;
        if (mat < 3)       { const float* B = em_w + mat * 129 * 64;     val = B[k*64+n] - B[(64+k)*64+n]; }
        else if (mat < 6)  { const float* B = em_w + (mat-3) * 129 * 64; val = B[(64+k)*64+n]; }
        else if (mat < 9)  { const float* B = ec_w + (mat-6) * 128 * 64; val = B[k*64+n] - B[(64+k)*64+n]; }
        else if (mat < 12) { const float* B = ec_w + (mat-9) * 128 * 64; val = B[(64+k)*64+n]; }
        else               { const float* B = (mat == 12) ? lw1 : lw2;   val = B[k*64+n]; }
        _Float16 h = (_Float16)val;
        _Float16 l = (_Float16)(val - (float)h);
        wh[(size_t)mat * 4096 + n * 64 + k] = h;
        wh[(size_t)(14 + mat) * 4096 + n * 64 + k] = l;
    }
}

// ---------------- scans ----------------
__global__ __launch_bounds__(256) void scan_blk(
        const int* __restrict__ cnt, int* __restrict__ bsum) {
    __shared__ int s[256];
    int t = threadIdx.x;
    int i = blockIdx.x * 256 + t;
    int c = (i < NKEY) ? cnt[i] : 0;
    s[t] = c; __syncthreads();
    for (int d = 1; d < 256; d <<= 1) {
        int v = (t >= d) ? s[t - d] : 0;
        __syncthreads(); s[t] += v; __syncthreads();
    }
    if (t == 255) bsum[blockIdx.x] = s[255];
}

__global__ __launch_bounds__(1024) void scan_top(
        const int* __restrict__ bsum, int* __restrict__ bofs, int nb) {
    __shared__ int s[1024];
    int t = threadIdx.x;
    int c = (t < nb) ? bsum[t] : 0;
    s[t] = c; __syncthreads();
    for (int d = 1; d < 1024; d <<= 1) {
        int v = (t >= d) ? s[t - d] : 0;
        __syncthreads(); s[t] += v; __syncthreads();
    }
    if (t < nb) bofs[t] = s[t] - c;  // exclusive
}

__global__ __launch_bounds__(256) void scan_fin(
        const int* __restrict__ cnt, const int* __restrict__ bofs,
        int* __restrict__ ofs) {
    __shared__ int s[256];
    int t = threadIdx.x;
    int i = blockIdx.x * 256 + t;
    int c = (i < NKEY) ? cnt[i] : 0;
    s[t] = c; __syncthreads();
    for (int d = 1; d < 256; d <<= 1) {
        int v = (t >= d) ? s[t - d] : 0;
        __syncthreads(); s[t] += v; __syncthreads();
    }
    if (i < NKEY) ofs[i] = bofs[blockIdx.x] + s[t] - c;  // exclusive
}

__device__ __forceinline__ void split8(const float* f, half8& h, half8& l) {
    #pragma unroll
    for (int j = 0; j < 8; ++j) {
        _Float16 hh = (_Float16)f[j];
        h[j] = hh; l[j] = (_Float16)(f[j] - (float)hh);
    }
}

// ---------------- fill (blocks < NB_COUNT) + uv0 / lin+uv GEMM -------------
// FILL: blocks [0,3125) do the CSR fill (no atomics; rank-based), remaining
// 782 blocks run the uv GEMM on x. DOLIN: apply x = relu(x@Wl + lb) (MFMA)
// before the uv GEMM, writing x back to global. B-frags read direct from
// global (8KB mats, L2-resident). LDS 27.6KB -> 5 blocks/CU.
template<bool FILL, bool DOLIN>
__global__ __launch_bounds__(256) void guv_kernel(
        const int* __restrict__ ei, const float* __restrict__ ef,
        const int* __restrict__ ofs, const uchar2* __restrict__ rank,
        unsigned* __restrict__ em_val, int* __restrict__ ec_val,
        const float* __restrict__ xg, float* __restrict__ xout,
        const _Float16* __restrict__ Wlh, const _Float16* __restrict__ Wll,
        const float* __restrict__ lbias,
        const _Float16* __restrict__ Wuh, const _Float16* __restrict__ Wul,
        const _Float16* __restrict__ Wvh, const _Float16* __restrict__ Wvl,
        const float* __restrict__ bias,
        _Float16* __restrict__ u, _Float16* __restrict__ v) {
    __shared__ _Float16 xh[64 * 72], xl[64 * 72];
    __shared__ _Float16 rp[4 * 16 * 72];
    const int t = threadIdx.x;
    int b = blockIdx.x;
    if constexpr (FILL) {
        if (b < NB_COUNT) {
            int e = b * 256 + t;
            if (e >= NE) return;
            int src = ei[e];
            int dst = ei[NE + e];
            int o = e / PER;
            uchar2 r = rank[e];
            int p1 = ofs[o * NN + src] + r.x;
            unsigned short eb = __half_as_ushort(__float2half_rn(ef[e]));
            em_val[p1] = ((unsigned)dst << 16) | (unsigned)eb;
            int p2 = ofs[4 * NN + dst] + r.y - NE;
            ec_val[p2] = src;
            return;
        }
        b -= NB_COUNT;
    }
    const int n0 = b * 64;

    { // stage x fp32 -> split: thread t -> node t>>2, 16 cols at (t&3)*16
        int node = t >> 2, k0 = (t & 3) * 16;
        int g = n0 + node;
        float f[16];
        if (g < NN) {
            const float4* xr4 = (const float4*)&xg[(size_t)g * HD + k0];
            *(float4*)&f[0] = xr4[0]; *(float4*)&f[4] = xr4[1];
            *(float4*)&f[8] = xr4[2]; *(float4*)&f[12] = xr4[3];
        } else {
            #pragma unroll
            for (int j = 0; j < 16; ++j) f[j] = 0.f;
        }
        half8 h0, l0, h1, l1;
        split8(f, h0, l0); split8(f + 8, h1, l1);
        *(half8*)&xh[node * 72 + k0] = h0; *(half8*)&xh[node * 72 + k0 + 8] = h1;
        *(half8*)&xl[node * 72 + k0] = l0; *(half8*)&xl[node * 72 + k0 + 8] = l1;
    }
    __syncthreads();

    const int w = t >> 6, lane = t & 63;
    const int quad = lane >> 4, l16 = lane & 15;
    const int m0 = w * 16;

    half8 ah0 = *(half8*)&xh[(m0 + l16) * 72 + quad * 8];
    half8 ah1 = *(half8*)&xh[(m0 + l16) * 72 + 32 + quad * 8];
    half8 al0 = *(half8*)&xl[(m0 + l16) * 72 + quad * 8];
    half8 al1 = *(half8*)&xl[(m0 + l16) * 72 + 32 + quad * 8];

    if constexpr (DOLIN) {
        float4v ax[4];
        #pragma unroll
        for (int nt = 0; nt < 4; ++nt) {
            int n = nt * 16 + l16;
            half8 bh0 = *(const half8*)&Wlh[n * 64 + quad * 8];
            half8 bh1 = *(const half8*)&Wlh[n * 64 + 32 + quad * 8];
            half8 bl0 = *(const half8*)&Wll[n * 64 + quad * 8];
            half8 bl1 = *(const half8*)&Wll[n * 64 + 32 + quad * 8];
            float4v acc = {0.f, 0.f, 0.f, 0.f};
            acc = MFMA16(ah0, bh0, acc); acc = MFMA16(ah1, bh1, acc);
            acc = MFMA16(al0, bh0, acc); acc = MFMA16(al1, bh1, acc);
            acc = MFMA16(ah0, bl0, acc); acc = MFMA16(ah1, bl1, acc);
            ax[nt] = acc;
        }
        __syncthreads();
        #pragma unroll
        for (int nt = 0; nt < 4; ++nt) {
            float bn = lbias[nt * 16 + l16];
            #pragma unroll
            for (int r = 0; r < 4; ++r) {
                float val = fmaxf(ax[nt][r] + bn, 0.f);
                int mrow = m0 + quad * 4 + r;
                _Float16 hh = (_Float16)val;
                xh[mrow * 72 + nt * 16 + l16] = hh;
                xl[mrow * 72 + nt * 16 + l16] = (_Float16)(val - (float)hh);
                int gn = n0 + mrow;
                if (gn < NN) xout[(size_t)gn * HD + nt * 16 + l16] = val;
            }
        }
        __syncthreads();
        ah0 = *(half8*)&xh[(m0 + l16) * 72 + quad * 8];
        ah1 = *(half8*)&xh[(m0 + l16) * 72 + 32 + quad * 8];
        al0 = *(half8*)&xl[(m0 + l16) * 72 + quad * 8];
        al1 = *(half8*)&xl[(m0 + l16) * 72 + 32 + quad * 8];
    }

    float4v au[4], av[4];
    #pragma unroll
    for (int nt = 0; nt < 4; ++nt) {
        int n = nt * 16 + l16;
        half8 bh0 = *(const half8*)&Wuh[n * 64 + quad * 8];
        half8 bh1 = *(const half8*)&Wuh[n * 64 + 32 + quad * 8];
        half8 bl0 = *(const half8*)&Wul[n * 64 + quad * 8];
        half8 bl1 = *(const half8*)&Wul[n * 64 + 32 + quad * 8];
        float4v acc = {0.f, 0.f, 0.f, 0.f};
        acc = MFMA16(ah0, bh0, acc); acc = MFMA16(ah1, bh1, acc);
        acc = MFMA16(al0, bh0, acc); acc = MFMA16(al1, bh1, acc);
        acc = MFMA16(ah0, bl0, acc); acc = MFMA16(ah1, bl1, acc);
        au[nt] = acc;
        half8 ch0 = *(const half8*)&Wvh[n * 64 + quad * 8];
        half8 ch1 = *(const half8*)&Wvh[n * 64 + 32 + quad * 8];
        half8 cl0 = *(const half8*)&Wvl[n * 64 + quad * 8];
        half8 cl1 = *(const half8*)&Wvl[n * 64 + 32 + quad * 8];
        float4v accv = {0.f, 0.f, 0.f, 0.f};
        accv = MFMA16(ah0, ch0, accv); accv = MFMA16(ah1, ch1, accv);
        accv = MFMA16(al0, ch0, accv); accv = MFMA16(al1, ch1, accv);
        accv = MFMA16(ah0, cl0, accv); accv = MFMA16(ah1, cl1, accv);
        av[nt] = accv;
    }

    _Float16* rpw = &rp[w * 16 * 72];
    #pragma unroll
    for (int nt = 0; nt < 4; ++nt) {
        float bn = bias[nt * 16 + l16];
        #pragma unroll
        for (int r = 0; r < 4; ++r)
            rpw[(quad * 4 + r) * 72 + nt * 16 + l16] = (_Float16)(au[nt][r] + bn);
    }
    int mr = lane >> 2, cr = (lane & 3) * 16;
    int gr = n0 + m0 + mr;
    if (gr < NN) {
        *(half8*)&u[(size_t)gr * HD + cr]     = *(half8*)&rpw[mr * 72 + cr];
        *(half8*)&u[(size_t)gr * HD + cr + 8] = *(half8*)&rpw[mr * 72 + cr + 8];
    }
    #pragma unroll
    for (int nt = 0; nt < 4; ++nt) {
        #pragma unroll
        for (int r = 0; r < 4; ++r)
            rpw[(quad * 4 + r) * 72 + nt * 16 + l16] = (_Float16)(av[nt][r]);
    }
    if (gr < NN) {
        *(half8*)&v[(size_t)gr * HD + cr]     = *(half8*)&rpw[mr * 72 + cr];
        *(half8*)&v[(size_t)gr * HD + cr + 8] = *(half8*)&rpw[mr * 72 + cr + 8];
    }
}

// ---------------- u/v via MFMA, split-fp16 (R5 version, known-good) --------
__global__ __launch_bounds__(256) void uv_mfma(
        const float* __restrict__ x,
        const _Float16* __restrict__ Wuh, const _Float16* __restrict__ Wul,
        const _Float16* __restrict__ Wvh, const _Float16* __restrict__ Wvl,
        const float* __restrict__ bias,
        _Float16* __restrict__ u, _Float16* __restrict__ v) {
    __shared__ _Float16 xh[64 * 72], xl[64 * 72];
    __shared__ _Float16 wuh[64 * 72], wul[64 * 72];
    __shared__ _Float16 wvh[64 * 72], wvl[64 * 72];
    __shared__ _Float16 rp[4 * 16 * 72];
    int t = threadIdx.x;
    int n0 = blockIdx.x * 64;

    {
        int node = t >> 2, k0 = (t & 3) * 16;
        int g = n0 + node;
        float f[16];
        if (g < NN) {
            const float4* xr = (const float4*)&x[(size_t)g * HD + k0];
            *(float4*)&f[0] = xr[0]; *(float4*)&f[4] = xr[1];
            *(float4*)&f[8] = xr[2]; *(float4*)&f[12] = xr[3];
        } else {
            #pragma unroll
            for (int j = 0; j < 16; ++j) f[j] = 0.f;
        }
        half8 h0, h1, l0, l1;
        split8(f, h0, l0); split8(f + 8, h1, l1);
        *(half8*)&xh[node * 72 + k0] = h0; *(half8*)&xh[node * 72 + k0 + 8] = h1;
        *(half8*)&xl[node * 72 + k0] = l0; *(half8*)&xl[node * 72 + k0 + 8] = l1;
    }
    {
        int n = t >> 2, c = (t & 3) * 16;
        *(half8*)&wuh[n * 72 + c]     = *(const half8*)&Wuh[n * 64 + c];
        *(half8*)&wuh[n * 72 + c + 8] = *(const half8*)&Wuh[n * 64 + c + 8];
        *(half8*)&wul[n * 72 + c]     = *(const half8*)&Wul[n * 64 + c];
        *(half8*)&wul[n * 72 + c + 8] = *(const half8*)&Wul[n * 64 + c + 8];
        *(half8*)&wvh[n * 72 + c]     = *(const half8*)&Wvh[n * 64 + c];
        *(half8*)&wvh[n * 72 + c + 8] = *(const half8*)&Wvh[n * 64 + c + 8];
        *(half8*)&wvl[n * 72 + c]     = *(const half8*)&Wvl[n * 64 + c];
        *(half8*)&wvl[n * 72 + c + 8] = *(const half8*)&Wvl[n * 64 + c + 8];
    }
    __syncthreads();

    int w = t >> 6, lane = t & 63;
    int quad = lane >> 4, l16 = lane & 15;
    int m0 = w * 16;
    half8 ah0 = *(half8*)&xh[(m0 + l16) * 72 + quad * 8];
    half8 ah1 = *(half8*)&xh[(m0 + l16) * 72 + 32 + quad * 8];
    half8 al0 = *(half8*)&xl[(m0 + l16) * 72 + quad * 8];
    half8 al1 = *(half8*)&xl[(m0 + l16) * 72 + 32 + quad * 8];

    float4v au[4], av[4];
    #pragma unroll
    for (int nt = 0; nt < 4; ++nt) {
        int n = nt * 16 + l16;
        half8 bh0 = *(half8*)&wuh[n * 72 + quad * 8];
        half8 bh1 = *(half8*)&wuh[n * 72 + 32 + quad * 8];
        half8 bl0 = *(half8*)&wul[n * 72 + quad * 8];
        half8 bl1 = *(half8*)&wul[n * 72 + 32 + quad * 8];
        float4v acc = {0.f, 0.f, 0.f, 0.f};
        acc = MFMA16(ah0, bh0, acc); acc = MFMA16(ah1, bh1, acc);
        acc = MFMA16(al0, bh0, acc); acc = MFMA16(al1, bh1, acc);
        acc = MFMA16(ah0, bl0, acc); acc = MFMA16(ah1, bl1, acc);
        au[nt] = acc;
        half8 ch0 = *(half8*)&wvh[n * 72 + quad * 8];
        half8 ch1 = *(half8*)&wvh[n * 72 + 32 + quad * 8];
        half8 cl0 = *(half8*)&wvl[n * 72 + quad * 8];
        half8 cl1 = *(half8*)&wvl[n * 72 + 32 + quad * 8];
        float4v accv = {0.f, 0.f, 0.f, 0.f};
        accv = MFMA16(ah0, ch0, accv); accv = MFMA16(ah1, ch1, accv);
        accv = MFMA16(al0, ch0, accv); accv = MFMA16(al1, ch1, accv);
        accv = MFMA16(ah0, cl0, accv); accv = MFMA16(ah1, cl1, accv);
        av[nt] = accv;
    }

    _Float16* rpw = &rp[w * 16 * 72];
    #pragma unroll
    for (int nt = 0; nt < 4; ++nt) {
        float bn = bias[nt * 16 + l16];
        #pragma unroll
        for (int r = 0; r < 4; ++r)
            rpw[(quad * 4 + r) * 72 + nt * 16 + l16] = (_Float16)(au[nt][r] + bn);
    }
    int mr = lane >> 2, cr = (lane & 3) * 16;
    int gr = n0 + m0 + mr;
    if (gr < NN) {
        *(half8*)&u[(size_t)gr * HD + cr]     = *(half8*)&rpw[mr * 72 + cr];
        *(half8*)&u[(size_t)gr * HD + cr + 8] = *(half8*)&rpw[mr * 72 + cr + 8];
    }
    #pragma unroll
    for (int nt = 0; nt < 4; ++nt) {
        #pragma unroll
        for (int r = 0; r < 4; ++r)
            rpw[(quad * 4 + r) * 72 + nt * 16 + l16] = (_Float16)(av[nt][r]);
    }
    if (gr < NN) {
        *(half8*)&v[(size_t)gr * HD + cr]     = *(half8*)&rpw[mr * 72 + cr];
        *(half8*)&v[(size_t)gr * HD + cr + 8] = *(half8*)&rpw[mr * 72 + cr + 8];
    }
}

// load 8 consecutive halves (16B aligned) -> 8 floats
__device__ __forceinline__ void load_h8(const __half* p, float* o) {
    float4 r = *(const float4*)p;
    __half2 h0 = *reinterpret_cast<__half2*>(&r.x);
    __half2 h1 = *reinterpret_cast<__half2*>(&r.y);
    __half2 h2 = *reinterpret_cast<__half2*>(&r.z);
    __half2 h3 = *reinterpret_cast<__half2*>(&r.w);
    float2 f0 = __half22float2(h0), f1 = __half22float2(h1);
    float2 f2 = __half22float2(h2), f3 = __half22float2(h3);
    o[0] = f0.x; o[1] = f0.y; o[2] = f1.x; o[3] = f1.y;
    o[4] = f2.x; o[5] = f2.y; o[6] = f3.x; o[7] = f3.y;
}

// ---------------- emulsion edge pass + fold (R5/R7, known-good) ------------
__global__ __launch_bounds__(256) void em_edge(
        const unsigned* __restrict__ em_val, const int* __restrict__ ofs,
        const __half* __restrict__ u, const __half* __restrict__ v,
        const float* __restrict__ we, float* __restrict__ x, int order) {
    int t = threadIdx.x;
    int node = blockIdx.x * 32 + (t >> 3);
    if (node >= NN) return;
    int f0 = (t & 7) * 8;
    int key = order * NN + node;
    int s0 = ofs[key], s1 = ofs[key + 1];
    float vn[8], wef[8], acc[8] = {};
    load_h8(&v[(size_t)node * HD + f0], vn);
    *(float4*)&wef[0] = *(const float4*)&we[f0];
    *(float4*)&wef[4] = *(const float4*)&we[f0 + 4];
    int p = s0;
    for (; p + 2 <= s1; p += 2) {
        unsigned e0 = em_val[p], e1 = em_val[p + 1];
        float u0[8], u1[8];
        load_h8(&u[(size_t)(e0 >> 16) * HD + f0], u0);
        load_h8(&u[(size_t)(e1 >> 16) * HD + f0], u1);
        float ef0 = __half2float(__ushort_as_half((unsigned short)(e0 & 0xffff)));
        float ef1 = __half2float(__ushort_as_half((unsigned short)(e1 & 0xffff)));
        #pragma unroll
        for (int j = 0; j < 8; ++j) {
            acc[j] += fmaxf(u0[j] + vn[j] + ef0 * wef[j], 0.f)
                    + fmaxf(u1[j] + vn[j] + ef1 * wef[j], 0.f);
        }
    }
    if (p < s1) {
        unsigned e0 = em_val[p];
        float u0[8];
        load_h8(&u[(size_t)(e0 >> 16) * HD + f0], u0);
        float ef0 = __half2float(__ushort_as_half((unsigned short)(e0 & 0xffff)));
        #pragma unroll
        for (int j = 0; j < 8; ++j)
            acc[j] += fmaxf(u0[j] + vn[j] + ef0 * wef[j], 0.f);
    }
    float xr[8];
    *(float4*)&xr[0] = *(const float4*)&x[(size_t)node * HD + f0];
    *(float4*)&xr[4] = *(const float4*)&x[(size_t)node * HD + f0 + 4];
    #pragma unroll
    for (int j = 0; j < 8; ++j) xr[j] = (xr[j] + acc[j]) * 0.5f;
    *(float4*)&x[(size_t)node * HD + f0] = *(float4*)&xr[0];
    *(float4*)&x[(size_t)node * HD + f0 + 4] = *(float4*)&xr[4];
}

// ---------------- edge conv pass: x[n] = max(0, max_e (u[n]+v[src])) -------
__global__ __launch_bounds__(256) void ec_edge(
        const int* __restrict__ ec_val, const int* __restrict__ ofs,
        const __half* __restrict__ u, const __half* __restrict__ v,
        float* __restrict__ x) {
    int t = threadIdx.x;
    int node = blockIdx.x * 32 + (t >> 3);
    if (node >= NN) return;
    int f0 = (t & 7) * 8;
    int s0 = ofs[4 * NN + node] - NE, s1 = ofs[4 * NN + node + 1] - NE;
    float un[8], m[8] = {};  // init 0: empty -> 0, and relu'd msgs >= 0
    load_h8(&u[(size_t)node * HD + f0], un);
    int p = s0;
    for (; p + 4 <= s1; p += 4) {
        int i0 = ec_val[p], i1 = ec_val[p + 1];
        int i2 = ec_val[p + 2], i3 = ec_val[p + 3];
        float v0[8], v1[8], v2[8], v3[8];
        load_h8(&v[(size_t)i0 * HD + f0], v0);
        load_h8(&v[(size_t)i1 * HD + f0], v1);
        load_h8(&v[(size_t)i2 * HD + f0], v2);
        load_h8(&v[(size_t)i3 * HD + f0], v3);
        #pragma unroll
        for (int j = 0; j < 8; ++j)
            m[j] = fmaxf(m[j], fmaxf(fmaxf(un[j] + v0[j], un[j] + v1[j]),
                                     fmaxf(un[j] + v2[j], un[j] + v3[j])));
    }
    for (; p < s1; ++p) {
        int i0 = ec_val[p];
        float v0[8];
        load_h8(&v[(size_t)i0 * HD + f0], v0);
        #pragma unroll
        for (int j = 0; j < 8; ++j) m[j] = fmaxf(m[j], un[j] + v0[j]);
    }
    *(float4*)&x[(size_t)node * HD + f0] = *(float4*)&m[0];
    *(float4*)&x[(size_t)node * HD + f0 + 4] = *(float4*)&m[4];
}

// ---------------- last ec pass fused with output projection ----------------
__global__ __launch_bounds__(256) void ec_out(
        const int* __restrict__ ec_val, const int* __restrict__ ofs,
        const __half* __restrict__ u, const __half* __restrict__ v,
        const float* __restrict__ ow, const float* __restrict__ ob,
        float* __restrict__ out) {
    __shared__ float xs[32][72];
    int t = threadIdx.x;
    int nl = t >> 3;
    int node = blockIdx.x * 32 + nl;
    int f0 = (t & 7) * 8;
    float m[8] = {};
    if (node < NN) {
        int s0 = ofs[4 * NN + node] - NE, s1 = ofs[4 * NN + node + 1] - NE;
        float un[8];
        load_h8(&u[(size_t)node * HD + f0], un);
        int p = s0;
        for (; p + 4 <= s1; p += 4) {
            int i0 = ec_val[p], i1 = ec_val[p + 1];
            int i2 = ec_val[p + 2], i3 = ec_val[p + 3];
            float v0[8], v1[8], v2[8], v3[8];
            load_h8(&v[(size_t)i0 * HD + f0], v0);
            load_h8(&v[(size_t)i1 * HD + f0], v1);
            load_h8(&v[(size_t)i2 * HD + f0], v2);
            load_h8(&v[(size_t)i3 * HD + f0], v3);
            #pragma unroll
            for (int j = 0; j < 8; ++j)
                m[j] = fmaxf(m[j], fmaxf(fmaxf(un[j] + v0[j], un[j] + v1[j]),
                                         fmaxf(un[j] + v2[j], un[j] + v3[j])));
        }
        for (; p < s1; ++p) {
            int i0 = ec_val[p];
            float v0[8];
            load_h8(&v[(size_t)i0 * HD + f0], v0);
            #pragma unroll
            for (int j = 0; j < 8; ++j) m[j] = fmaxf(m[j], un[j] + v0[j]);
        }
    }
    #pragma unroll
    for (int j = 0; j < 8; ++j) xs[nl][f0 + j] = m[j];
    __syncthreads();
    for (int idx = t; idx < 32 * 10; idx += 256) {
        int n = idx / 10, f = idx - n * 10;
        int g = blockIdx.x * 32 + n;
        if (g >= NN) continue;
        float acc = ob[f];
        #pragma unroll
        for (int k = 0; k < HD; ++k) acc += xs[n][k] * ow[k * 10 + f];
        out[(size_t)g * 10 + f] = acc;
    }
}

extern "C" void kernel_launch(void* const* d_in, const int* in_sizes, int n_in,
                              void* d_out, int out_size, void* d_ws, size_t ws_size,
                              hipStream_t stream) {
    const float* x_in  = (const float*)d_in[0];
    const int*   ei    = (const int*)d_in[1];
    const float* ef    = (const float*)d_in[2];
    const float* lw[3] = {(const float*)d_in[3], (const float*)d_in[5], (const float*)d_in[7]};
    const float* lb[3] = {(const float*)d_in[4], (const float*)d_in[6], (const float*)d_in[8]};
    const float* em_w  = (const float*)d_in[9];
    const float* em_b  = (const float*)d_in[10];
    const float* ec_w  = (const float*)d_in[11];
    const float* ec_b  = (const float*)d_in[12];
    const float* ow    = (const float*)d_in[13];
    const float* ob    = (const float*)d_in[14];
    float* out = (float*)d_out;

    char* wsb = (char*)d_ws;
    size_t off = 0;
    auto alloc = [&](size_t bytes) {
        void* p = wsb + off;
        off = (off + bytes + 255) & ~(size_t)255;
        return p;
    };
    float*     x      = (float*)alloc((size_t)NN * HD * 4);
    _Float16*  u      = (_Float16*)alloc((size_t)NN * HD * 2);
    _Float16*  v      = (_Float16*)alloc((size_t)NN * HD * 2);
    int*       cnt    = (int*)alloc((size_t)NKEY * 4);
    int*       ofs    = (int*)alloc((size_t)NKEY * 4);
    int*       bsum   = (int*)alloc((size_t)1024 * 4);
    int*       bofs   = (int*)alloc((size_t)1024 * 4);
    uchar2*    rank   = (uchar2*)alloc((size_t)NE * 2);
    unsigned*  em_val = (unsigned*)alloc((size_t)NE * 4);
    int*       ec_val = (int*)alloc((size_t)NE * 4);
    _Float16*  wh     = (_Float16*)alloc((size_t)28 * 4096 * 2);
    (void)ws_size; (void)in_sizes; (void)n_in; (void)out_size;

    const int gb_nodes = (NN + 63) / 64;   // 782
    const int gb_n8    = (NN + 31) / 32;   // 1563
    const int gb_keys  = NKEY / 256;       // 977

    auto Wm  = [&](int mat) { return wh + (size_t)mat * 4096; };
    auto Wl_ = [&](int mat) { return wh + (size_t)(14 + mat) * 4096; };

    // ---- setup: count + lin0 + prep_w fused; scan; fill || uv0 ----
    hipMemsetAsync(cnt, 0, (size_t)NKEY * 4, stream);
    setup_kernel<<<NB_COUNT + NB_LIN + NB_PREP, 256, 0, stream>>>(
        ei, cnt, rank, x_in, lw[0], lb[0], x, em_w, ec_w, lw[1], lw[2], wh);
    scan_blk<<<gb_keys, 256, 0, stream>>>(cnt, bsum);
    scan_top<<<1, 1024, 0, stream>>>(bsum, bofs, gb_keys);
    scan_fin<<<gb_keys, 256, 0, stream>>>(cnt, bofs, ofs);
    // fill (3125 blocks) || uv0 with layer-0 em weights (782 blocks)
    guv_kernel<true, false><<<NB_COUNT + gb_nodes, 256, 0, stream>>>(
        ei, ef, ofs, rank, em_val, ec_val,
        x, nullptr, nullptr, nullptr, nullptr,
        Wm(0), Wl_(0), Wm(3), Wl_(3), em_b, u, v);

    // ---- network ----
    for (int i = 0; i < 3; ++i) {
        const float* we = em_w + (size_t)i * 129 * HD + 128 * HD;
        const float* bi = em_b + (size_t)i * HD;
        for (int o = 0; o < 4; ++o) {
            em_edge<<<gb_n8, 256, 0, stream>>>(em_val, ofs, (const __half*)u,
                                               (const __half*)v, we, x, o);
            if (o < 3)
                uv_mfma<<<gb_nodes, 256, 0, stream>>>(
                    x, Wm(i), Wl_(i), Wm(3 + i), Wl_(3 + i), bi, u, v);
        }
        if (i < 2) {
            // x = relu(x @ lw[i+1] + lb[i+1]); then uv with layer i+1 weights
            guv_kernel<false, true><<<gb_nodes, 256, 0, stream>>>(
                nullptr, nullptr, nullptr, nullptr, nullptr, nullptr,
                x, x, Wm(12 + i), Wl_(12 + i), lb[i + 1],
                Wm(i + 1), Wl_(i + 1), Wm(4 + i), Wl_(4 + i),
                em_b + (size_t)(i + 1) * HD, u, v);
        } else {
            uv_mfma<<<gb_nodes, 256, 0, stream>>>(
                x, Wm(6), Wl_(6), Wm(9), Wl_(9), ec_b, u, v);
        }
    }

    for (int j = 0; j < 2; ++j) {
        ec_edge<<<gb_n8, 256, 0, stream>>>(ec_val, ofs, (const __half*)u,
                                           (const __half*)v, x);
        uv_mfma<<<gb_nodes, 256, 0, stream>>>(
            x, Wm(7 + j), Wl_(7 + j), Wm(10 + j), Wl_(10 + j),
            ec_b + (size_t)(j + 1) * HD, u, v);
    }
    ec_out<<<gb_n8, 256, 0, stream>>>(ec_val, ofs, (const __half*)u,
                                      (const __half*)v, ow, ob, out);
}